// Round 17
// baseline (221.690 us; speedup 1.0000x reference)
//
#include <hip/hip_runtime.h>
#include <math.h>

#define FB 512
#define TB 256
#define PLANE (FB * TB)
typedef long long i64;
typedef _Float16 f16;
typedef _Float16 f16x8 __attribute__((ext_vector_type(8)));
typedef _Float16 f16x4 __attribute__((ext_vector_type(4)));
typedef float f32x4 __attribute__((ext_vector_type(4)));

#define MFMA16(a, b, c) __builtin_amdgcn_mfma_f32_16x16x32_f16(a, b, c, 0, 0, 0)

// ---------- generic 64x64 transpose+cvt tile: dst[c0+t][r0+f] = src[r0+f][c0+t]
__device__ __forceinline__ void tcvt_tile(const float* __restrict__ src,
                                          f16* __restrict__ dst,
                                          int sstride, int dstride,
                                          int r0, int c0, int tid,
                                          float (*ld)[65]) {
    const int lrr = tid >> 4, lc = (tid & 15) * 4;
    f32x4 v0 = *(const f32x4*)&src[(i64)(r0 + lrr + 0) * sstride + c0 + lc];
    f32x4 v1 = *(const f32x4*)&src[(i64)(r0 + lrr + 16) * sstride + c0 + lc];
    f32x4 v2 = *(const f32x4*)&src[(i64)(r0 + lrr + 32) * sstride + c0 + lc];
    f32x4 v3 = *(const f32x4*)&src[(i64)(r0 + lrr + 48) * sstride + c0 + lc];
#pragma unroll
    for (int j = 0; j < 4; ++j) {
        ld[lrr + 0][lc + j] = v0[j];
        ld[lrr + 16][lc + j] = v1[j];
        ld[lrr + 32][lc + j] = v2[j];
        ld[lrr + 48][lc + j] = v3[j];
    }
    __syncthreads();
    const int tr2 = tid >> 3, fc = (tid & 7) * 8;
#pragma unroll
    for (int pass = 0; pass < 2; ++pass) {
        const int t = tr2 + pass * 32;
        f16x8 o;
#pragma unroll
        for (int j = 0; j < 8; ++j) o[j] = (f16)ld[fc + j][t];
        *(f16x8*)&dst[(i64)(c0 + t) * dstride + r0 + fc] = o;
    }
}

// ================= prologue: x-tcvt || W1^T-tcvt || W2 cvt || zeros || beff ===
__global__ __launch_bounds__(256) void k_pre2(const float* __restrict__ X,
                                              f16* __restrict__ O,
                                              const float* __restrict__ W1,
                                              f16* __restrict__ W1t,
                                              const float* __restrict__ W2,
                                              f16* __restrict__ W2h,
                                              float* __restrict__ zrs,
                                              const float* __restrict__ b1,
                                              const float* __restrict__ b2,
                                              float* __restrict__ beff) {
    __shared__ float ld[64][65];
    const int bid = blockIdx.x;
    const int tid = threadIdx.x;
    if (bid < 8192) {
        const int p = bid >> 5;
        const int f0 = ((bid >> 2) & 7) * 64, t0 = (bid & 3) * 64;
        tcvt_tile(X + (i64)p * PLANE, O + (i64)p * PLANE, TB, FB, f0, t0, tid, ld);
    } else if (bid < 8256) {
        const int w = bid - 8192;
        tcvt_tile(W1, W1t, FB, FB, (w >> 3) * 64, (w & 7) * 64, tid, ld);
    } else if (bid < 8384) {
        const i64 idx = ((i64)(bid - 8256) * 256 + tid) * 8;
        const float4 a = *(const float4*)&W2[idx];
        const float4 b = *(const float4*)&W2[idx + 4];
        f16x8 o;
        o[0] = (f16)a.x; o[1] = (f16)a.y; o[2] = (f16)a.z; o[3] = (f16)a.w;
        o[4] = (f16)b.x; o[5] = (f16)b.y; o[6] = (f16)b.z; o[7] = (f16)b.w;
        *(f16x8*)&W2h[idx] = o;
    } else if (bid == 8384) {
        zrs[tid] = 0.f;
        zrs[tid + 256] = 0.f;
    } else {
        // beff[m] = dot(W2[m,:], b1) + b2[m]; one m per wave, coalesced.
        const int m = (bid - 8385) * 4 + (tid >> 6);
        const int lane = tid & 63;
        const float* w2r = W2 + (i64)m * FB + lane * 8;
        const f32x4 a0 = *(const f32x4*)(w2r);
        const f32x4 a1 = *(const f32x4*)(w2r + 4);
        const f32x4 c0 = *(const f32x4*)(b1 + lane * 8);
        const f32x4 c1 = *(const f32x4*)(b1 + lane * 8 + 4);
        float acc = 0.f;
#pragma unroll
        for (int j = 0; j < 4; ++j) acc = fmaf(a0[j], c0[j], acc);
#pragma unroll
        for (int j = 0; j < 4; ++j) acc = fmaf(a1[j], c1[j], acc);
#pragma unroll
        for (int o = 32; o > 0; o >>= 1) acc += __shfl_xor(acc, o);
        if (lane == 0) beff[m] = acc + b2[m];
    }
}

// ---------- real MFMA GEMM body: Out[t][m] (f16) = sum_k A[m][k]*In[t][k] + bias[m]
__device__ __forceinline__ void rgemm_body(const f16* __restrict__ A,
                                           const f16* __restrict__ In,
                                           const float* __restrict__ bias,
                                           f16* __restrict__ Out,
                                           int t0, int m0, int slab,
                                           f16 (*Asx)[40], f16 (*Bsx)[40]) {
    const f16* Bsrc = In + (i64)slab * PLANE;
    f16* Odst = Out + (i64)slab * PLANE;
    const int tid = threadIdx.x;
    const int wave = tid >> 6, lane = tid & 63;
    const int wm = wave >> 1, wn = wave & 1;
    const int lr = lane & 15, lg = lane >> 4;
    const int srow = tid >> 2, sgrp = (tid & 3) * 8;

    f32x4 acc[4][4] = {};
    f16x8 nA[2], nB[2];
#pragma unroll
    for (int i = 0; i < 2; ++i) {
        const int row = i * 64 + srow;
        nA[i] = *(const f16x8*)(A + (i64)(m0 + row) * FB + sgrp);
        nB[i] = *(const f16x8*)(Bsrc + (i64)(t0 + row) * FB + sgrp);
    }
#pragma unroll
    for (int i = 0; i < 2; ++i) {
        const int row = i * 64 + srow;
        *(f16x8*)&Asx[row][sgrp] = nA[i];
        *(f16x8*)&Bsx[row][sgrp] = nB[i];
    }
    __syncthreads();

#pragma unroll 1
    for (int kt = 0; kt < 16; ++kt) {
        if (kt < 15) {
            const int k0 = (kt + 1) * 32;
#pragma unroll
            for (int i = 0; i < 2; ++i) {
                const int row = i * 64 + srow;
                nA[i] = *(const f16x8*)(A + (i64)(m0 + row) * FB + k0 + sgrp);
                nB[i] = *(const f16x8*)(Bsrc + (i64)(t0 + row) * FB + k0 + sgrp);
            }
        }
        f16x8 aA[4], bB[4];
#pragma unroll
        for (int mf = 0; mf < 4; ++mf)
            aA[mf] = *(const f16x8*)&Asx[wm * 64 + mf * 16 + lr][lg * 8];
#pragma unroll
        for (int nf = 0; nf < 4; ++nf)
            bB[nf] = *(const f16x8*)&Bsx[wn * 64 + nf * 16 + lr][lg * 8];
#pragma unroll
        for (int nf = 0; nf < 4; ++nf)
#pragma unroll
            for (int mf = 0; mf < 4; ++mf)
                acc[mf][nf] = MFMA16(aA[mf], bB[nf], acc[mf][nf]);
        __syncthreads();
        if (kt < 15) {
#pragma unroll
            for (int i = 0; i < 2; ++i) {
                const int row = i * 64 + srow;
                *(f16x8*)&Asx[row][sgrp] = nA[i];
                *(f16x8*)&Bsx[row][sgrp] = nB[i];
            }
        }
        __syncthreads();
    }

#pragma unroll
    for (int mf = 0; mf < 4; ++mf) {
        const int m = m0 + wm * 64 + mf * 16 + lg * 4;
        const float4 bv = *(const float4*)&bias[m];
        const float bb[4] = {bv.x, bv.y, bv.z, bv.w};
#pragma unroll
        for (int nf = 0; nf < 4; ++nf) {
            const int t = t0 + wn * 64 + nf * 16 + lr;
            f16x4 o;
#pragma unroll
            for (int r = 0; r < 4; ++r) o[r] = (f16)(acc[mf][nf][r] + bb[r]);
            *(f16x4*)&Odst[(i64)t * FB + m] = o;
        }
    }
}

// 3D-grid launcher (used for Weff = W2@W1: A=W1t, In=W2h, bias=0)
__global__ __launch_bounds__(256, 2) void k_rgemm(const f16* __restrict__ A,
                                                  const f16* __restrict__ In,
                                                  const float* __restrict__ bias,
                                                  f16* __restrict__ Out) {
    __shared__ f16 Asx[128][40], Bsx[128][40];
    rgemm_body(A, In, bias, Out, blockIdx.x * 128, blockIdx.y * 128, blockIdx.z,
               Asx, Bsx);
}

// XCD-grouped 1D launcher for logits GEMM (r13: +L2 tile reuse)
__global__ __launch_bounds__(256, 2) void k_rgemm_swz(const f16* __restrict__ A,
                                                      const f16* __restrict__ In,
                                                      const float* __restrict__ bias,
                                                      f16* __restrict__ Out) {
    __shared__ f16 Asx[128][40], Bsx[128][40];
    const int id = blockIdx.x;
    const int xcd = id & 7, q = id >> 3;
    const int m = q & 3;
    const int G = ((q >> 2) << 3) | xcd;
    rgemm_body(A, In, bias, Out, (G & 1) * 128, m * 128, G >> 1, Asx, Bsx);
}

// ================= fused softmax + conjFFT/mul/FFT, radix-8 three-step =======
// z[p] at (lane=p%64, reg=p/64); natural in/out; direct coalesced global I/O
// (lane-stride-1 element => 128B/instruction). x4-WIDE: each wave owns 4 t's;
// 3x fft512x4 calls (conj t0/t1, conj t2/t3, fwd P0..P3) halve the serial
// LDS round-trip chains per t and give 2x butterfly ILP under each lgkmcnt.
// Two XOR-swizzled float4 regions per wave (16 KB); all static reg indices.

#define TWO_PI_OVER_512 0.012271846303085129f
#define TWO_PI_OVER_64 0.0981747704246810387f
#define R2C 0.70710678118654752f

__device__ __forceinline__ int swz(int r, int c) { return r * 8 + (c ^ (r & 7)); }

template <int SGN>
__device__ __forceinline__ void fft8(float xr[8], float xi[8]) {
    const float sg = (float)SGN;   // W8 = e^{SGN*i*2pi/8}
    float t0r = xr[0] + xr[4], t0i = xi[0] + xi[4];
    float u0r = xr[0] - xr[4], u0i = xi[0] - xi[4];
    float t1r = xr[1] + xr[5], t1i = xi[1] + xi[5];
    float d1r = xr[1] - xr[5], d1i = xi[1] - xi[5];
    float u1r = R2C * (d1r - sg * d1i), u1i = R2C * (sg * d1r + d1i);
    float t2r = xr[2] + xr[6], t2i = xi[2] + xi[6];
    float d2r = xr[2] - xr[6], d2i = xi[2] - xi[6];
    float u2r = -sg * d2i, u2i = sg * d2r;
    float t3r = xr[3] + xr[7], t3i = xi[3] + xi[7];
    float d3r = xr[3] - xr[7], d3i = xi[3] - xi[7];
    float u3r = -R2C * (d3r + sg * d3i), u3i = R2C * (sg * d3r - d3i);
    float p0r = t0r + t2r, p0i = t0i + t2i, q0r = t0r - t2r, q0i = t0i - t2i;
    float p1r = t1r + t3r, p1i = t1i + t3i;
    float q1r = -sg * (t1i - t3i), q1i = sg * (t1r - t3r);
    float p2r = u0r + u2r, p2i = u0i + u2i, q2r = u0r - u2r, q2i = u0i - u2i;
    float p3r = u1r + u3r, p3i = u1i + u3i;
    float q3r = -sg * (u1i - u3i), q3i = sg * (u1r - u3r);
    xr[0] = p0r + p1r; xi[0] = p0i + p1i;
    xr[4] = p0r - p1r; xi[4] = p0i - p1i;
    xr[2] = q0r + q1r; xi[2] = q0i + q1i;
    xr[6] = q0r - q1r; xi[6] = q0i - q1i;
    xr[1] = p2r + p3r; xi[1] = p2i + p3i;
    xr[5] = p2r - p3r; xi[5] = p2i - p3i;
    xr[3] = q2r + q3r; xi[3] = q2i + q3i;
    xr[7] = q2r - q3r; xi[7] = q2i - q3i;
}

// 4 independent 512-pt FFTs: arrays A,B packed in L1, arrays C,D in L2.
template <int SGN>
__device__ __forceinline__ void fft512x4(float Ar[8], float Ai[8],
                                         float Br[8], float Bi[8],
                                         float Cr[8], float Ci[8],
                                         float Dr[8], float Di[8], int lane,
                                         float4* __restrict__ L1,
                                         float4* __restrict__ L2,
                                         const float w1c[7], const float w1s[7],
                                         const float w2c[7], const float w2s[7]) {
    const float sg = (float)SGN;
    fft8<SGN>(Ar, Ai);
    fft8<SGN>(Br, Bi);
    fft8<SGN>(Cr, Ci);
    fft8<SGN>(Dr, Di);
#pragma unroll
    for (int m = 1; m < 8; ++m) {
        const float wc = w1c[m - 1], ws = sg * w1s[m - 1];
        float tr = Ar[m], ti = Ai[m];
        Ar[m] = tr * wc - ti * ws; Ai[m] = tr * ws + ti * wc;
        tr = Br[m]; ti = Bi[m];
        Br[m] = tr * wc - ti * ws; Bi[m] = tr * ws + ti * wc;
        tr = Cr[m]; ti = Ci[m];
        Cr[m] = tr * wc - ti * ws; Ci[m] = tr * ws + ti * wc;
        tr = Dr[m]; ti = Di[m];
        Dr[m] = tr * wc - ti * ws; Di[m] = tr * ws + ti * wc;
    }
    // transpose 1: linear write (lane, m) ; permuted read (a8+8b8, m8)
#pragma unroll
    for (int m = 0; m < 8; ++m) {
        L1[swz(lane, m)] = make_float4(Ar[m], Ai[m], Br[m], Bi[m]);
        L2[swz(lane, m)] = make_float4(Cr[m], Ci[m], Dr[m], Di[m]);
    }
    {
        const int a8 = lane & 7, m8 = lane >> 3;
#pragma unroll
        for (int b8 = 0; b8 < 8; ++b8) {
            const float4 v1 = L1[swz(a8 + 8 * b8, m8)];
            const float4 v2 = L2[swz(a8 + 8 * b8, m8)];
            Ar[b8] = v1.x; Ai[b8] = v1.y; Br[b8] = v1.z; Bi[b8] = v1.w;
            Cr[b8] = v2.x; Ci[b8] = v2.y; Dr[b8] = v2.z; Di[b8] = v2.w;
        }
    }
    fft8<SGN>(Ar, Ai);
    fft8<SGN>(Br, Bi);
    fft8<SGN>(Cr, Ci);
    fft8<SGN>(Dr, Di);
#pragma unroll
    for (int n = 1; n < 8; ++n) {
        const float wc = w2c[n - 1], ws = sg * w2s[n - 1];
        float tr = Ar[n], ti = Ai[n];
        Ar[n] = tr * wc - ti * ws; Ai[n] = tr * ws + ti * wc;
        tr = Br[n]; ti = Bi[n];
        Br[n] = tr * wc - ti * ws; Bi[n] = tr * ws + ti * wc;
        tr = Cr[n]; ti = Ci[n];
        Cr[n] = tr * wc - ti * ws; Ci[n] = tr * ws + ti * wc;
        tr = Dr[n]; ti = Di[n];
        Dr[n] = tr * wc - ti * ws; Di[n] = tr * ws + ti * wc;
    }
    // transpose 2: scatter write (m2+8n, a2) ; linear read (lane, j)
    {
        const int a2 = lane & 7, m2 = lane >> 3;
#pragma unroll
        for (int n = 0; n < 8; ++n) {
            L1[swz(m2 + 8 * n, a2)] = make_float4(Ar[n], Ai[n], Br[n], Bi[n]);
            L2[swz(m2 + 8 * n, a2)] = make_float4(Cr[n], Ci[n], Dr[n], Di[n]);
        }
    }
#pragma unroll
    for (int j = 0; j < 8; ++j) {
        const float4 v1 = L1[swz(lane, j)];
        const float4 v2 = L2[swz(lane, j)];
        Ar[j] = v1.x; Ai[j] = v1.y; Br[j] = v1.z; Bi[j] = v1.w;
        Cr[j] = v2.x; Ci[j] = v2.y; Dr[j] = v2.z; Di[j] = v2.w;
    }
    fft8<SGN>(Ar, Ai);
    fft8<SGN>(Br, Bi);
    fft8<SGN>(Cr, Ci);
    fft8<SGN>(Dr, Di);
}

__device__ __forceinline__ float wave_max(float v) {
#pragma unroll
    for (int m = 1; m <= 32; m <<= 1) v = fmaxf(v, __shfl_xor(v, m));
    return v;
}
__device__ __forceinline__ float wave_sum(float v) {
#pragma unroll
    for (int m = 1; m <= 32; m <<= 1) v += __shfl_xor(v, m);
    return v;
}

__device__ __forceinline__ void softmax8(float w[8]) {
    float mx = w[0];
#pragma unroll
    for (int j = 1; j < 8; ++j) mx = fmaxf(mx, w[j]);
    mx = wave_max(mx);
    float sm = 0.f;
#pragma unroll
    for (int j = 0; j < 8; ++j) { w[j] = __expf(w[j] - mx); sm += w[j]; }
    sm = wave_sum(sm);
    const float inv = 1.0f / sm;
#pragma unroll
    for (int j = 0; j < 8; ++j) w[j] *= inv;
}

// One wave processes 4 t's of one plane-pair: conj x4 (t0,t1), conj x4 (t2,t3),
// fwd x4 (P0..P3). Direct coalesced loads/stores.
__device__ __forceinline__ void fftconv_wave4(const f16* __restrict__ xh,
                                              const f16* __restrict__ logits,
                                              f16* __restrict__ conv,
                                              int t1a, int cs, int lane,
                                              float4* L1, float4* L2) {
    const int b = cs >> 4, d = cs & 15;
    const int pre = b * 32 + d;
    const int pim = pre + 16;

    float w1c[7], w1s[7], w2c[7], w2s[7];
    {
        float s1, c1;
        __sincosf((float)lane * TWO_PI_OVER_512, &s1, &c1);
        w1c[0] = c1; w1s[0] = s1;
#pragma unroll
        for (int m = 1; m < 7; ++m) {
            const float pc = w1c[m - 1], ps = w1s[m - 1];
            w1c[m] = pc * c1 - ps * s1;
            w1s[m] = pc * s1 + ps * c1;
        }
        float s2, c2;
        __sincosf((float)(lane & 7) * TWO_PI_OVER_64, &s2, &c2);
        w2c[0] = c2; w2s[0] = s2;
#pragma unroll
        for (int n = 1; n < 7; ++n) {
            const float pc = w2c[n - 1], ps = w2s[n - 1];
            w2c[n] = pc * c2 - ps * s2;
            w2s[n] = pc * s2 + ps * c2;
        }
    }

    const f16* Hre = xh + (i64)pre * PLANE;
    const f16* Him = xh + (i64)pim * PLANE;
    const f16* Wre = logits + (i64)pre * PLANE;
    const f16* Wim = logits + (i64)pim * PLANE;
    f16* Cre = conv + (i64)pre * PLANE;
    f16* Cim = conv + (i64)pim * PLANE;

    const i64 rb0 = (i64)t1a * FB + lane;
    const i64 rb1 = rb0 + FB;
    const i64 rb2 = rb1 + FB;
    const i64 rb3 = rb2 + FB;

    float p0r[8], p0i[8], p1r[8], p1i[8], p2r[8], p2i[8], p3r[8], p3i[8];
    // ---- conj phase t0,t1: arrays (h0,w0,h1,w1)
    {
        float h0r[8], h0i[8], w0r[8], w0i[8], h1r[8], h1i[8], w1r[8], w1i[8];
#pragma unroll
        for (int j = 0; j < 8; ++j) {
            h0r[j] = (float)Hre[rb0 + 64 * j];
            h0i[j] = (float)Him[rb0 + 64 * j];
            w0r[j] = (float)Wre[rb0 + 64 * j];
            w0i[j] = (float)Wim[rb0 + 64 * j];
            h1r[j] = (float)Hre[rb1 + 64 * j];
            h1i[j] = (float)Him[rb1 + 64 * j];
            w1r[j] = (float)Wre[rb1 + 64 * j];
            w1i[j] = (float)Wim[rb1 + 64 * j];
        }
        softmax8(w0r);
        softmax8(w0i);
        softmax8(w1r);
        softmax8(w1i);
        fft512x4<1>(h0r, h0i, w0r, w0i, h1r, h1i, w1r, w1i, lane, L1, L2,
                    w1c, w1s, w2c, w2s);
#pragma unroll
        for (int j = 0; j < 8; ++j) {
            p0r[j] = (h0r[j] * w0r[j] - h0i[j] * w0i[j]) * (1.0f / 512.0f);
            p0i[j] = (h0r[j] * w0i[j] + h0i[j] * w0r[j]) * (1.0f / 512.0f);
            p1r[j] = (h1r[j] * w1r[j] - h1i[j] * w1i[j]) * (1.0f / 512.0f);
            p1i[j] = (h1r[j] * w1i[j] + h1i[j] * w1r[j]) * (1.0f / 512.0f);
        }
    }
    // ---- conj phase t2,t3
    {
        float h0r[8], h0i[8], w0r[8], w0i[8], h1r[8], h1i[8], w1r[8], w1i[8];
#pragma unroll
        for (int j = 0; j < 8; ++j) {
            h0r[j] = (float)Hre[rb2 + 64 * j];
            h0i[j] = (float)Him[rb2 + 64 * j];
            w0r[j] = (float)Wre[rb2 + 64 * j];
            w0i[j] = (float)Wim[rb2 + 64 * j];
            h1r[j] = (float)Hre[rb3 + 64 * j];
            h1i[j] = (float)Him[rb3 + 64 * j];
            w1r[j] = (float)Wre[rb3 + 64 * j];
            w1i[j] = (float)Wim[rb3 + 64 * j];
        }
        softmax8(w0r);
        softmax8(w0i);
        softmax8(w1r);
        softmax8(w1i);
        fft512x4<1>(h0r, h0i, w0r, w0i, h1r, h1i, w1r, w1i, lane, L1, L2,
                    w1c, w1s, w2c, w2s);
#pragma unroll
        for (int j = 0; j < 8; ++j) {
            p2r[j] = (h0r[j] * w0r[j] - h0i[j] * w0i[j]) * (1.0f / 512.0f);
            p2i[j] = (h0r[j] * w0i[j] + h0i[j] * w0r[j]) * (1.0f / 512.0f);
            p3r[j] = (h1r[j] * w1r[j] - h1i[j] * w1i[j]) * (1.0f / 512.0f);
            p3i[j] = (h1r[j] * w1i[j] + h1i[j] * w1r[j]) * (1.0f / 512.0f);
        }
    }
    // ---- forward phase: all four products at once
    fft512x4<-1>(p0r, p0i, p1r, p1i, p2r, p2i, p3r, p3i, lane, L1, L2,
                 w1c, w1s, w2c, w2s);

    // direct coalesced stores (128B/instruction per wave)
#pragma unroll
    for (int s = 0; s < 8; ++s) {
        Cre[rb0 + 64 * s] = (f16)p0r[s];
        Cim[rb0 + 64 * s] = (f16)p0i[s];
        Cre[rb1 + 64 * s] = (f16)p1r[s];
        Cim[rb1 + 64 * s] = (f16)p1i[s];
        Cre[rb2 + 64 * s] = (f16)p2r[s];
        Cim[rb2 + 64 * s] = (f16)p2i[s];
        Cre[rb3 + 64 * s] = (f16)p3r[s];
        Cim[rb3 + 64 * s] = (f16)p3i[s];
    }
}

// Grid 2048: block = 4 waves x 4 t = 16 t's of one plane-pair; XCD-swizzled.
// id bits: [2:0]=xcd (cs high), [6:3]=tg, [10:7]=cs low. Bijective.
__global__ __launch_bounds__(256, 2) void k_fftconv_all(const f16* __restrict__ xh,
                                                        const f16* __restrict__ logits,
                                                        f16* __restrict__ conv) {
    __shared__ float4 LDS[4][1024];   // 64 KB: two 8KB regions per wave
    const int id = blockIdx.x;
    const int xcd = id & 7, r = id >> 3;
    const int tg = r & 15;
    const int cs = (xcd << 4) | (r >> 4);
    const int wave = threadIdx.x >> 6, lane = threadIdx.x & 63;
    fftconv_wave4(xh, logits, conv, tg * 16 + wave * 4, cs, lane,
                  LDS[wave], LDS[wave] + 512);
}

// transpose_out: f16 [t][f] conv plane p -> f32 [f][t] out plane p
__global__ __launch_bounds__(256) void k_transpose_out(const f16* __restrict__ C,
                                                       float* __restrict__ O) {
    __shared__ float ld[64][65];
    const int tid = threadIdx.x;
    const int p = blockIdx.z;
    const f16* src = C + (i64)p * PLANE;
    float* dst = O + (i64)p * PLANE;
    const int t0 = blockIdx.x * 64, f0 = blockIdx.y * 64;
    const int tr = tid >> 3, fc = (tid & 7) * 8;
    f16x8 u0 = *(const f16x8*)&src[(i64)(t0 + tr) * FB + f0 + fc];
    f16x8 u1 = *(const f16x8*)&src[(i64)(t0 + tr + 32) * FB + f0 + fc];
#pragma unroll
    for (int j = 0; j < 8; ++j) {
        ld[fc + j][tr] = (float)u0[j];
        ld[fc + j][tr + 32] = (float)u1[j];
    }
    __syncthreads();
    const int fr = tid >> 4, tc = (tid & 15) * 4;
#pragma unroll
    for (int i = 0; i < 4; ++i) {
        const int f = fr + i * 16;
        float4 o;
        o.x = ld[f][tc + 0]; o.y = ld[f][tc + 1];
        o.z = ld[f][tc + 2]; o.w = ld[f][tc + 3];
        *(float4*)&dst[(i64)(f0 + f) * TB + t0 + tc] = o;
    }
}

extern "C" void kernel_launch(void* const* d_in, const int* in_sizes, int n_in,
                              void* d_out, int out_size, void* d_ws, size_t ws_size,
                              hipStream_t stream) {
    (void)in_sizes; (void)n_in; (void)out_size; (void)ws_size;
    const float* x = (const float*)d_in[0];
    const float* W1 = (const float*)d_in[1];
    const float* b1 = (const float*)d_in[2];
    const float* W2 = (const float*)d_in[3];
    const float* b2 = (const float*)d_in[4];
    float* out = (float*)d_out;

    char* ws = (char*)d_ws;
    const i64 TENB = (i64)67108864;                       // f16 full tensor bytes
    f16* Weff  = (f16*)(ws);                              // 512 KB
    float* beff = (float*)(ws + 524288);                  // 2 KB (pad to 4 KB)
    f16* W1t  = (f16*)(ws + 528384);                      // 512 KB
    f16* W2h  = (f16*)(ws + 1052672);                     // 512 KB
    float* zrs = (float*)(ws + 1576960);                  // 2 KB (pad to 4 KB)
    f16* xh     = (f16*)(ws + 1581056);                   // 67.1 MB
    f16* logits = (f16*)(ws + 1581056 + TENB);            // 67.1 MB
    f16* conv   = (f16*)(ws + 1581056 + 2 * TENB);        // 67.1 MB

    // L1: x-tcvt || W1^T-tcvt || W2-cvt || zeros || beff (wave-parallel)
    k_pre2<<<dim3(8513), dim3(256), 0, stream>>>(x, xh, W1, W1t, W2, W2h, zrs, b1, b2, beff);
    // L2: Weff = W2 @ W1 via MFMA
    k_rgemm<<<dim3(4, 4, 1), dim3(256), 0, stream>>>(W1t, W2h, zrs, Weff);
    // L3: logits = Weff @ X + beff (XCD-grouped: In-tile shared via L2)
    k_rgemm_swz<<<dim3(2048), dim3(256), 0, stream>>>(Weff, xh, beff, logits);
    // L4: fftconv all 128 pairs -> conv f16 (x4-wide waves)
    k_fftconv_all<<<dim3(2048), dim3(256), 0, stream>>>(xh, logits, conv);
    // L5: transpose conv -> out (f32 [f][t], all 256 planes)
    k_transpose_out<<<dim3(4, 8, 256), dim3(256), 0, stream>>>(conv, out);
}

// Round 18
// 212.349 us; speedup vs baseline: 1.0440x; 1.0440x over previous
//
#include <hip/hip_runtime.h>
#include <math.h>

#define FB 512
#define TB 256
#define PLANE (FB * TB)
typedef long long i64;
typedef _Float16 f16;
typedef _Float16 f16x8 __attribute__((ext_vector_type(8)));
typedef _Float16 f16x4 __attribute__((ext_vector_type(4)));
typedef float f32x4 __attribute__((ext_vector_type(4)));

#define MFMA16(a, b, c) __builtin_amdgcn_mfma_f32_16x16x32_f16(a, b, c, 0, 0, 0)

// ---------- generic 64x64 transpose+cvt tile: dst[c0+t][r0+f] = src[r0+f][c0+t]
__device__ __forceinline__ void tcvt_tile(const float* __restrict__ src,
                                          f16* __restrict__ dst,
                                          int sstride, int dstride,
                                          int r0, int c0, int tid,
                                          float (*ld)[65]) {
    const int lrr = tid >> 4, lc = (tid & 15) * 4;
    f32x4 v0 = *(const f32x4*)&src[(i64)(r0 + lrr + 0) * sstride + c0 + lc];
    f32x4 v1 = *(const f32x4*)&src[(i64)(r0 + lrr + 16) * sstride + c0 + lc];
    f32x4 v2 = *(const f32x4*)&src[(i64)(r0 + lrr + 32) * sstride + c0 + lc];
    f32x4 v3 = *(const f32x4*)&src[(i64)(r0 + lrr + 48) * sstride + c0 + lc];
#pragma unroll
    for (int j = 0; j < 4; ++j) {
        ld[lrr + 0][lc + j] = v0[j];
        ld[lrr + 16][lc + j] = v1[j];
        ld[lrr + 32][lc + j] = v2[j];
        ld[lrr + 48][lc + j] = v3[j];
    }
    __syncthreads();
    const int tr2 = tid >> 3, fc = (tid & 7) * 8;
#pragma unroll
    for (int pass = 0; pass < 2; ++pass) {
        const int t = tr2 + pass * 32;
        f16x8 o;
#pragma unroll
        for (int j = 0; j < 8; ++j) o[j] = (f16)ld[fc + j][t];
        *(f16x8*)&dst[(i64)(c0 + t) * dstride + r0 + fc] = o;
    }
}

// ================= prologue: x-tcvt || W1^T-tcvt || W2 cvt || zeros || beff ===
__global__ __launch_bounds__(256) void k_pre2(const float* __restrict__ X,
                                              f16* __restrict__ O,
                                              const float* __restrict__ W1,
                                              f16* __restrict__ W1t,
                                              const float* __restrict__ W2,
                                              f16* __restrict__ W2h,
                                              float* __restrict__ zrs,
                                              const float* __restrict__ b1,
                                              const float* __restrict__ b2,
                                              float* __restrict__ beff) {
    __shared__ float ld[64][65];
    const int bid = blockIdx.x;
    const int tid = threadIdx.x;
    if (bid < 8192) {
        const int p = bid >> 5;
        const int f0 = ((bid >> 2) & 7) * 64, t0 = (bid & 3) * 64;
        tcvt_tile(X + (i64)p * PLANE, O + (i64)p * PLANE, TB, FB, f0, t0, tid, ld);
    } else if (bid < 8256) {
        const int w = bid - 8192;
        tcvt_tile(W1, W1t, FB, FB, (w >> 3) * 64, (w & 7) * 64, tid, ld);
    } else if (bid < 8384) {
        const i64 idx = ((i64)(bid - 8256) * 256 + tid) * 8;
        const float4 a = *(const float4*)&W2[idx];
        const float4 b = *(const float4*)&W2[idx + 4];
        f16x8 o;
        o[0] = (f16)a.x; o[1] = (f16)a.y; o[2] = (f16)a.z; o[3] = (f16)a.w;
        o[4] = (f16)b.x; o[5] = (f16)b.y; o[6] = (f16)b.z; o[7] = (f16)b.w;
        *(f16x8*)&W2h[idx] = o;
    } else if (bid == 8384) {
        zrs[tid] = 0.f;
        zrs[tid + 256] = 0.f;
    } else {
        // beff[m] = dot(W2[m,:], b1) + b2[m]; one m per wave, coalesced.
        const int m = (bid - 8385) * 4 + (tid >> 6);
        const int lane = tid & 63;
        const float* w2r = W2 + (i64)m * FB + lane * 8;
        const f32x4 a0 = *(const f32x4*)(w2r);
        const f32x4 a1 = *(const f32x4*)(w2r + 4);
        const f32x4 c0 = *(const f32x4*)(b1 + lane * 8);
        const f32x4 c1 = *(const f32x4*)(b1 + lane * 8 + 4);
        float acc = 0.f;
#pragma unroll
        for (int j = 0; j < 4; ++j) acc = fmaf(a0[j], c0[j], acc);
#pragma unroll
        for (int j = 0; j < 4; ++j) acc = fmaf(a1[j], c1[j], acc);
#pragma unroll
        for (int o = 32; o > 0; o >>= 1) acc += __shfl_xor(acc, o);
        if (lane == 0) beff[m] = acc + b2[m];
    }
}

// ---------- real MFMA GEMM body: Out[t][m] (f16) = sum_k A[m][k]*In[t][k] + bias[m]
__device__ __forceinline__ void rgemm_body(const f16* __restrict__ A,
                                           const f16* __restrict__ In,
                                           const float* __restrict__ bias,
                                           f16* __restrict__ Out,
                                           int t0, int m0, int slab,
                                           f16 (*Asx)[40], f16 (*Bsx)[40]) {
    const f16* Bsrc = In + (i64)slab * PLANE;
    f16* Odst = Out + (i64)slab * PLANE;
    const int tid = threadIdx.x;
    const int wave = tid >> 6, lane = tid & 63;
    const int wm = wave >> 1, wn = wave & 1;
    const int lr = lane & 15, lg = lane >> 4;
    const int srow = tid >> 2, sgrp = (tid & 3) * 8;

    f32x4 acc[4][4] = {};
    f16x8 nA[2], nB[2];
#pragma unroll
    for (int i = 0; i < 2; ++i) {
        const int row = i * 64 + srow;
        nA[i] = *(const f16x8*)(A + (i64)(m0 + row) * FB + sgrp);
        nB[i] = *(const f16x8*)(Bsrc + (i64)(t0 + row) * FB + sgrp);
    }
#pragma unroll
    for (int i = 0; i < 2; ++i) {
        const int row = i * 64 + srow;
        *(f16x8*)&Asx[row][sgrp] = nA[i];
        *(f16x8*)&Bsx[row][sgrp] = nB[i];
    }
    __syncthreads();

#pragma unroll 1
    for (int kt = 0; kt < 16; ++kt) {
        if (kt < 15) {
            const int k0 = (kt + 1) * 32;
#pragma unroll
            for (int i = 0; i < 2; ++i) {
                const int row = i * 64 + srow;
                nA[i] = *(const f16x8*)(A + (i64)(m0 + row) * FB + k0 + sgrp);
                nB[i] = *(const f16x8*)(Bsrc + (i64)(t0 + row) * FB + k0 + sgrp);
            }
        }
        f16x8 aA[4], bB[4];
#pragma unroll
        for (int mf = 0; mf < 4; ++mf)
            aA[mf] = *(const f16x8*)&Asx[wm * 64 + mf * 16 + lr][lg * 8];
#pragma unroll
        for (int nf = 0; nf < 4; ++nf)
            bB[nf] = *(const f16x8*)&Bsx[wn * 64 + nf * 16 + lr][lg * 8];
#pragma unroll
        for (int nf = 0; nf < 4; ++nf)
#pragma unroll
            for (int mf = 0; mf < 4; ++mf)
                acc[mf][nf] = MFMA16(aA[mf], bB[nf], acc[mf][nf]);
        __syncthreads();
        if (kt < 15) {
#pragma unroll
            for (int i = 0; i < 2; ++i) {
                const int row = i * 64 + srow;
                *(f16x8*)&Asx[row][sgrp] = nA[i];
                *(f16x8*)&Bsx[row][sgrp] = nB[i];
            }
        }
        __syncthreads();
    }

#pragma unroll
    for (int mf = 0; mf < 4; ++mf) {
        const int m = m0 + wm * 64 + mf * 16 + lg * 4;
        const float4 bv = *(const float4*)&bias[m];
        const float bb[4] = {bv.x, bv.y, bv.z, bv.w};
#pragma unroll
        for (int nf = 0; nf < 4; ++nf) {
            const int t = t0 + wn * 64 + nf * 16 + lr;
            f16x4 o;
#pragma unroll
            for (int r = 0; r < 4; ++r) o[r] = (f16)(acc[mf][nf][r] + bb[r]);
            *(f16x4*)&Odst[(i64)t * FB + m] = o;
        }
    }
}

// 3D-grid launcher (used for Weff = W2@W1: A=W1t, In=W2h, bias=0)
__global__ __launch_bounds__(256, 2) void k_rgemm(const f16* __restrict__ A,
                                                  const f16* __restrict__ In,
                                                  const float* __restrict__ bias,
                                                  f16* __restrict__ Out) {
    __shared__ f16 Asx[128][40], Bsx[128][40];
    rgemm_body(A, In, bias, Out, blockIdx.x * 128, blockIdx.y * 128, blockIdx.z,
               Asx, Bsx);
}

// XCD-grouped 1D launcher for logits GEMM (r13: +L2 tile reuse)
__global__ __launch_bounds__(256, 2) void k_rgemm_swz(const f16* __restrict__ A,
                                                      const f16* __restrict__ In,
                                                      const float* __restrict__ bias,
                                                      f16* __restrict__ Out) {
    __shared__ f16 Asx[128][40], Bsx[128][40];
    const int id = blockIdx.x;
    const int xcd = id & 7, q = id >> 3;
    const int m = q & 3;
    const int G = ((q >> 2) << 3) | xcd;
    rgemm_body(A, In, bias, Out, (G & 1) * 128, m * 128, G >> 1, Asx, Bsx);
}

// ================= fused softmax + conjFFT/mul/FFT, radix-8 three-step =======
// r16 config (x2-wide, 32 KB LDS, direct coalesced I/O) + r18 additions:
// explicit upfront prefetch of BOTH sequences (compiler wasn't hoisting:
// VGPR=80) and s_setprio(1) around the FFT compute clusters (waves are
// barrier-free/phase-drifted -> priority arbitration pays, m191 regime).

#define TWO_PI_OVER_512 0.012271846303085129f
#define TWO_PI_OVER_64 0.0981747704246810387f
#define R2C 0.70710678118654752f

__device__ __forceinline__ int swz(int r, int c) { return r * 8 + (c ^ (r & 7)); }

template <int SGN>
__device__ __forceinline__ void fft8(float xr[8], float xi[8]) {
    const float sg = (float)SGN;   // W8 = e^{SGN*i*2pi/8}
    float t0r = xr[0] + xr[4], t0i = xi[0] + xi[4];
    float u0r = xr[0] - xr[4], u0i = xi[0] - xi[4];
    float t1r = xr[1] + xr[5], t1i = xi[1] + xi[5];
    float d1r = xr[1] - xr[5], d1i = xi[1] - xi[5];
    float u1r = R2C * (d1r - sg * d1i), u1i = R2C * (sg * d1r + d1i);
    float t2r = xr[2] + xr[6], t2i = xi[2] + xi[6];
    float d2r = xr[2] - xr[6], d2i = xi[2] - xi[6];
    float u2r = -sg * d2i, u2i = sg * d2r;
    float t3r = xr[3] + xr[7], t3i = xi[3] + xi[7];
    float d3r = xr[3] - xr[7], d3i = xi[3] - xi[7];
    float u3r = -R2C * (d3r + sg * d3i), u3i = R2C * (sg * d3r - d3i);
    float p0r = t0r + t2r, p0i = t0i + t2i, q0r = t0r - t2r, q0i = t0i - t2i;
    float p1r = t1r + t3r, p1i = t1i + t3i;
    float q1r = -sg * (t1i - t3i), q1i = sg * (t1r - t3r);
    float p2r = u0r + u2r, p2i = u0i + u2i, q2r = u0r - u2r, q2i = u0i - u2i;
    float p3r = u1r + u3r, p3i = u1i + u3i;
    float q3r = -sg * (u1i - u3i), q3i = sg * (u1r - u3r);
    xr[0] = p0r + p1r; xi[0] = p0i + p1i;
    xr[4] = p0r - p1r; xi[4] = p0i - p1i;
    xr[2] = q0r + q1r; xi[2] = q0i + q1i;
    xr[6] = q0r - q1r; xi[6] = q0i - q1i;
    xr[1] = p2r + p3r; xi[1] = p2i + p3i;
    xr[5] = p2r - p3r; xi[5] = p2i - p3i;
    xr[3] = q2r + q3r; xi[3] = q2i + q3i;
    xr[7] = q2r - q3r; xi[7] = q2i - q3i;
}

template <int SGN>
__device__ __forceinline__ void fft512x2(float ar[8], float ai[8],
                                         float br[8], float bi[8], int lane,
                                         float4* __restrict__ L,
                                         const float w1c[7], const float w1s[7],
                                         const float w2c[7], const float w2s[7]) {
    const float sg = (float)SGN;
    fft8<SGN>(ar, ai);
    fft8<SGN>(br, bi);
#pragma unroll
    for (int m = 1; m < 8; ++m) {
        const float wc = w1c[m - 1], ws = sg * w1s[m - 1];
        float tr = ar[m], ti = ai[m];
        ar[m] = tr * wc - ti * ws; ai[m] = tr * ws + ti * wc;
        tr = br[m]; ti = bi[m];
        br[m] = tr * wc - ti * ws; bi[m] = tr * ws + ti * wc;
    }
    // transpose 1: linear write (lane, m) ; permuted read (a8+8b8, m8)
#pragma unroll
    for (int m = 0; m < 8; ++m)
        L[swz(lane, m)] = make_float4(ar[m], ai[m], br[m], bi[m]);
    {
        const int a8 = lane & 7, m8 = lane >> 3;
#pragma unroll
        for (int b8 = 0; b8 < 8; ++b8) {
            const float4 v = L[swz(a8 + 8 * b8, m8)];
            ar[b8] = v.x; ai[b8] = v.y; br[b8] = v.z; bi[b8] = v.w;
        }
    }
    fft8<SGN>(ar, ai);
    fft8<SGN>(br, bi);
#pragma unroll
    for (int n = 1; n < 8; ++n) {
        const float wc = w2c[n - 1], ws = sg * w2s[n - 1];
        float tr = ar[n], ti = ai[n];
        ar[n] = tr * wc - ti * ws; ai[n] = tr * ws + ti * wc;
        tr = br[n]; ti = bi[n];
        br[n] = tr * wc - ti * ws; bi[n] = tr * ws + ti * wc;
    }
    // transpose 2: scatter write (m2+8n, a2) ; linear read (lane, j)
    {
        const int a2 = lane & 7, m2 = lane >> 3;
#pragma unroll
        for (int n = 0; n < 8; ++n)
            L[swz(m2 + 8 * n, a2)] = make_float4(ar[n], ai[n], br[n], bi[n]);
    }
#pragma unroll
    for (int j = 0; j < 8; ++j) {
        const float4 v = L[swz(lane, j)];
        ar[j] = v.x; ai[j] = v.y; br[j] = v.z; bi[j] = v.w;
    }
    fft8<SGN>(ar, ai);
    fft8<SGN>(br, bi);
}

__device__ __forceinline__ float wave_max(float v) {
#pragma unroll
    for (int m = 1; m <= 32; m <<= 1) v = fmaxf(v, __shfl_xor(v, m));
    return v;
}
__device__ __forceinline__ float wave_sum(float v) {
#pragma unroll
    for (int m = 1; m <= 32; m <<= 1) v += __shfl_xor(v, m);
    return v;
}

__device__ __forceinline__ void softmax8(float w[8]) {
    float mx = w[0];
#pragma unroll
    for (int j = 1; j < 8; ++j) mx = fmaxf(mx, w[j]);
    mx = wave_max(mx);
    float sm = 0.f;
#pragma unroll
    for (int j = 0; j < 8; ++j) { w[j] = __expf(w[j] - mx); sm += w[j]; }
    sm = wave_sum(sm);
    const float inv = 1.0f / sm;
#pragma unroll
    for (int j = 0; j < 8; ++j) w[j] *= inv;
}

__device__ __forceinline__ void fftconv_block(const f16* __restrict__ xh,
                                              const f16* __restrict__ logits,
                                              f16* __restrict__ conv,
                                              int tblk, int cs,
                                              int wave, int lane, float4* L) {
    const int b = cs >> 4, d = cs & 15;
    const int pre = b * 32 + d;
    const int pim = pre + 16;

    float w1c[7], w1s[7], w2c[7], w2s[7];
    {
        float s1, c1;
        __sincosf((float)lane * TWO_PI_OVER_512, &s1, &c1);
        w1c[0] = c1; w1s[0] = s1;
#pragma unroll
        for (int m = 1; m < 7; ++m) {
            const float pc = w1c[m - 1], ps = w1s[m - 1];
            w1c[m] = pc * c1 - ps * s1;
            w1s[m] = pc * s1 + ps * c1;
        }
        float s2, c2;
        __sincosf((float)(lane & 7) * TWO_PI_OVER_64, &s2, &c2);
        w2c[0] = c2; w2s[0] = s2;
#pragma unroll
        for (int n = 1; n < 7; ++n) {
            const float pc = w2c[n - 1], ps = w2s[n - 1];
            w2c[n] = pc * c2 - ps * s2;
            w2s[n] = pc * s2 + ps * c2;
        }
    }

    const f16* Hre = xh + (i64)pre * PLANE;
    const f16* Him = xh + (i64)pim * PLANE;
    const f16* Wre = logits + (i64)pre * PLANE;
    const f16* Wim = logits + (i64)pim * PLANE;
    f16* Cre = conv + (i64)pre * PLANE;
    f16* Cim = conv + (i64)pim * PLANE;

    const int t1a = tblk * 8 + wave * 2;
    const i64 rb0 = (i64)t1a * FB + lane;
    const i64 rb1 = rb0 + FB;

    // explicit upfront prefetch of BOTH sequences (static indices only)
    float h0r[8], h0i[8], w0r[8], w0i[8];
    float h1r[8], h1i[8], w1r[8], w1i[8];
#pragma unroll
    for (int j = 0; j < 8; ++j) {
        h0r[j] = (float)Hre[rb0 + 64 * j];
        h0i[j] = (float)Him[rb0 + 64 * j];
        w0r[j] = (float)Wre[rb0 + 64 * j];
        w0i[j] = (float)Wim[rb0 + 64 * j];
    }
#pragma unroll
    for (int j = 0; j < 8; ++j) {
        h1r[j] = (float)Hre[rb1 + 64 * j];
        h1i[j] = (float)Him[rb1 + 64 * j];
        w1r[j] = (float)Wre[rb1 + 64 * j];
        w1i[j] = (float)Wim[rb1 + 64 * j];
    }

    float p0r[8], p0i[8], p1r[8], p1i[8];
    {
        softmax8(w0r);
        softmax8(w0i);
        __builtin_amdgcn_s_setprio(1);
        fft512x2<1>(h0r, h0i, w0r, w0i, lane, L, w1c, w1s, w2c, w2s);
        __builtin_amdgcn_s_setprio(0);
#pragma unroll
        for (int j = 0; j < 8; ++j) {
            p0r[j] = (h0r[j] * w0r[j] - h0i[j] * w0i[j]) * (1.0f / 512.0f);
            p0i[j] = (h0r[j] * w0i[j] + h0i[j] * w0r[j]) * (1.0f / 512.0f);
        }
    }
    {
        softmax8(w1r);
        softmax8(w1i);
        __builtin_amdgcn_s_setprio(1);
        fft512x2<1>(h1r, h1i, w1r, w1i, lane, L, w1c, w1s, w2c, w2s);
        __builtin_amdgcn_s_setprio(0);
#pragma unroll
        for (int j = 0; j < 8; ++j) {
            p1r[j] = (h1r[j] * w1r[j] - h1i[j] * w1i[j]) * (1.0f / 512.0f);
            p1i[j] = (h1r[j] * w1i[j] + h1i[j] * w1r[j]) * (1.0f / 512.0f);
        }
    }
    __builtin_amdgcn_s_setprio(1);
    fft512x2<-1>(p0r, p0i, p1r, p1i, lane, L, w1c, w1s, w2c, w2s);
    __builtin_amdgcn_s_setprio(0);

    // direct coalesced stores: instruction s covers 128B contiguous per wave
#pragma unroll
    for (int s = 0; s < 8; ++s) {
        Cre[rb0 + 64 * s] = (f16)p0r[s];
        Cim[rb0 + 64 * s] = (f16)p0i[s];
        Cre[rb1 + 64 * s] = (f16)p1r[s];
        Cim[rb1 + 64 * s] = (f16)p1i[s];
    }
}

// Single-pass fftconv over all 128 pairs, XCD-swizzled (r13).
__global__ __launch_bounds__(256, 2) void k_fftconv_all(const f16* __restrict__ xh,
                                                        const f16* __restrict__ logits,
                                                        f16* __restrict__ conv) {
    __shared__ float4 LDS[4][512];   // 32 KB
    const int id = blockIdx.x;
    const int xcd = id & 7, r = id >> 3;
    const int tblk = r & 31;
    const int cs = (xcd << 4) | (r >> 5);
    const int wave = threadIdx.x >> 6, lane = threadIdx.x & 63;
    fftconv_block(xh, logits, conv, tblk, cs, wave, lane, LDS[wave]);
}

// transpose_out: f16 [t][f] conv plane p -> f32 [f][t] out plane p
__global__ __launch_bounds__(256) void k_transpose_out(const f16* __restrict__ C,
                                                       float* __restrict__ O) {
    __shared__ float ld[64][65];
    const int tid = threadIdx.x;
    const int p = blockIdx.z;
    const f16* src = C + (i64)p * PLANE;
    float* dst = O + (i64)p * PLANE;
    const int t0 = blockIdx.x * 64, f0 = blockIdx.y * 64;
    const int tr = tid >> 3, fc = (tid & 7) * 8;
    f16x8 u0 = *(const f16x8*)&src[(i64)(t0 + tr) * FB + f0 + fc];
    f16x8 u1 = *(const f16x8*)&src[(i64)(t0 + tr + 32) * FB + f0 + fc];
#pragma unroll
    for (int j = 0; j < 8; ++j) {
        ld[fc + j][tr] = (float)u0[j];
        ld[fc + j][tr + 32] = (float)u1[j];
    }
    __syncthreads();
    const int fr = tid >> 4, tc = (tid & 15) * 4;
#pragma unroll
    for (int i = 0; i < 4; ++i) {
        const int f = fr + i * 16;
        float4 o;
        o.x = ld[f][tc + 0]; o.y = ld[f][tc + 1];
        o.z = ld[f][tc + 2]; o.w = ld[f][tc + 3];
        *(float4*)&dst[(i64)(f0 + f) * TB + t0 + tc] = o;
    }
}

extern "C" void kernel_launch(void* const* d_in, const int* in_sizes, int n_in,
                              void* d_out, int out_size, void* d_ws, size_t ws_size,
                              hipStream_t stream) {
    (void)in_sizes; (void)n_in; (void)out_size; (void)ws_size;
    const float* x = (const float*)d_in[0];
    const float* W1 = (const float*)d_in[1];
    const float* b1 = (const float*)d_in[2];
    const float* W2 = (const float*)d_in[3];
    const float* b2 = (const float*)d_in[4];
    float* out = (float*)d_out;

    char* ws = (char*)d_ws;
    const i64 TENB = (i64)67108864;                       // f16 full tensor bytes
    f16* Weff  = (f16*)(ws);                              // 512 KB
    float* beff = (float*)(ws + 524288);                  // 2 KB (pad to 4 KB)
    f16* W1t  = (f16*)(ws + 528384);                      // 512 KB
    f16* W2h  = (f16*)(ws + 1052672);                     // 512 KB
    float* zrs = (float*)(ws + 1576960);                  // 2 KB (pad to 4 KB)
    f16* xh     = (f16*)(ws + 1581056);                   // 67.1 MB
    f16* logits = (f16*)(ws + 1581056 + TENB);            // 67.1 MB
    f16* conv   = (f16*)(ws + 1581056 + 2 * TENB);        // 67.1 MB

    // L1: x-tcvt || W1^T-tcvt || W2-cvt || zeros || beff (wave-parallel)
    k_pre2<<<dim3(8513), dim3(256), 0, stream>>>(x, xh, W1, W1t, W2, W2h, zrs, b1, b2, beff);
    // L2: Weff = W2 @ W1 via MFMA
    k_rgemm<<<dim3(4, 4, 1), dim3(256), 0, stream>>>(W1t, W2h, zrs, Weff);
    // L3: logits = Weff @ X + beff (XCD-grouped: In-tile shared via L2)
    k_rgemm_swz<<<dim3(2048), dim3(256), 0, stream>>>(Weff, xh, beff, logits);
    // L4: fftconv all 128 pairs -> conv f16
    k_fftconv_all<<<dim3(4096), dim3(256), 0, stream>>>(xh, logits, conv);
    // L5: transpose conv -> out (f32 [f][t], all 256 planes)
    k_transpose_out<<<dim3(4, 8, 256), dim3(256), 0, stream>>>(conv, out);
}

// Round 19
// 209.110 us; speedup vs baseline: 1.0602x; 1.0155x over previous
//
#include <hip/hip_runtime.h>
#include <math.h>

#define FB 512
#define TB 256
#define PLANE (FB * TB)
typedef long long i64;
typedef _Float16 f16;
typedef _Float16 f16x8 __attribute__((ext_vector_type(8)));
typedef _Float16 f16x4 __attribute__((ext_vector_type(4)));
typedef float f32x4 __attribute__((ext_vector_type(4)));

#define MFMA16(a, b, c) __builtin_amdgcn_mfma_f32_16x16x32_f16(a, b, c, 0, 0, 0)

// ---------- generic 64x64 transpose+cvt tile: dst[c0+t][r0+f] = src[r0+f][c0+t]
__device__ __forceinline__ void tcvt_tile(const float* __restrict__ src,
                                          f16* __restrict__ dst,
                                          int sstride, int dstride,
                                          int r0, int c0, int tid,
                                          float (*ld)[65]) {
    const int lrr = tid >> 4, lc = (tid & 15) * 4;
    f32x4 v0 = *(const f32x4*)&src[(i64)(r0 + lrr + 0) * sstride + c0 + lc];
    f32x4 v1 = *(const f32x4*)&src[(i64)(r0 + lrr + 16) * sstride + c0 + lc];
    f32x4 v2 = *(const f32x4*)&src[(i64)(r0 + lrr + 32) * sstride + c0 + lc];
    f32x4 v3 = *(const f32x4*)&src[(i64)(r0 + lrr + 48) * sstride + c0 + lc];
#pragma unroll
    for (int j = 0; j < 4; ++j) {
        ld[lrr + 0][lc + j] = v0[j];
        ld[lrr + 16][lc + j] = v1[j];
        ld[lrr + 32][lc + j] = v2[j];
        ld[lrr + 48][lc + j] = v3[j];
    }
    __syncthreads();
    const int tr2 = tid >> 3, fc = (tid & 7) * 8;
#pragma unroll
    for (int pass = 0; pass < 2; ++pass) {
        const int t = tr2 + pass * 32;
        f16x8 o;
#pragma unroll
        for (int j = 0; j < 8; ++j) o[j] = (f16)ld[fc + j][t];
        *(f16x8*)&dst[(i64)(c0 + t) * dstride + r0 + fc] = o;
    }
}

// ================= prologue: x-tcvt || W1^T-tcvt || W2 cvt || zeros || beff ===
__global__ __launch_bounds__(256) void k_pre2(const float* __restrict__ X,
                                              f16* __restrict__ O,
                                              const float* __restrict__ W1,
                                              f16* __restrict__ W1t,
                                              const float* __restrict__ W2,
                                              f16* __restrict__ W2h,
                                              float* __restrict__ zrs,
                                              const float* __restrict__ b1,
                                              const float* __restrict__ b2,
                                              float* __restrict__ beff) {
    __shared__ float ld[64][65];
    const int bid = blockIdx.x;
    const int tid = threadIdx.x;
    if (bid < 8192) {
        const int p = bid >> 5;
        const int f0 = ((bid >> 2) & 7) * 64, t0 = (bid & 3) * 64;
        tcvt_tile(X + (i64)p * PLANE, O + (i64)p * PLANE, TB, FB, f0, t0, tid, ld);
    } else if (bid < 8256) {
        const int w = bid - 8192;
        tcvt_tile(W1, W1t, FB, FB, (w >> 3) * 64, (w & 7) * 64, tid, ld);
    } else if (bid < 8384) {
        const i64 idx = ((i64)(bid - 8256) * 256 + tid) * 8;
        const float4 a = *(const float4*)&W2[idx];
        const float4 b = *(const float4*)&W2[idx + 4];
        f16x8 o;
        o[0] = (f16)a.x; o[1] = (f16)a.y; o[2] = (f16)a.z; o[3] = (f16)a.w;
        o[4] = (f16)b.x; o[5] = (f16)b.y; o[6] = (f16)b.z; o[7] = (f16)b.w;
        *(f16x8*)&W2h[idx] = o;
    } else if (bid == 8384) {
        zrs[tid] = 0.f;
        zrs[tid + 256] = 0.f;
    } else {
        // beff[m] = dot(W2[m,:], b1) + b2[m]; one m per wave, coalesced.
        const int m = (bid - 8385) * 4 + (tid >> 6);
        const int lane = tid & 63;
        const float* w2r = W2 + (i64)m * FB + lane * 8;
        const f32x4 a0 = *(const f32x4*)(w2r);
        const f32x4 a1 = *(const f32x4*)(w2r + 4);
        const f32x4 c0 = *(const f32x4*)(b1 + lane * 8);
        const f32x4 c1 = *(const f32x4*)(b1 + lane * 8 + 4);
        float acc = 0.f;
#pragma unroll
        for (int j = 0; j < 4; ++j) acc = fmaf(a0[j], c0[j], acc);
#pragma unroll
        for (int j = 0; j < 4; ++j) acc = fmaf(a1[j], c1[j], acc);
#pragma unroll
        for (int o = 32; o > 0; o >>= 1) acc += __shfl_xor(acc, o);
        if (lane == 0) beff[m] = acc + b2[m];
    }
}

// ---------- real MFMA GEMM body: Out[t][m] (f16) = sum_k A[m][k]*In[t][k] + bias[m]
__device__ __forceinline__ void rgemm_body(const f16* __restrict__ A,
                                           const f16* __restrict__ In,
                                           const float* __restrict__ bias,
                                           f16* __restrict__ Out,
                                           int t0, int m0, int slab,
                                           f16 (*Asx)[40], f16 (*Bsx)[40]) {
    const f16* Bsrc = In + (i64)slab * PLANE;
    f16* Odst = Out + (i64)slab * PLANE;
    const int tid = threadIdx.x;
    const int wave = tid >> 6, lane = tid & 63;
    const int wm = wave >> 1, wn = wave & 1;
    const int lr = lane & 15, lg = lane >> 4;
    const int srow = tid >> 2, sgrp = (tid & 3) * 8;

    f32x4 acc[4][4] = {};
    f16x8 nA[2], nB[2];
#pragma unroll
    for (int i = 0; i < 2; ++i) {
        const int row = i * 64 + srow;
        nA[i] = *(const f16x8*)(A + (i64)(m0 + row) * FB + sgrp);
        nB[i] = *(const f16x8*)(Bsrc + (i64)(t0 + row) * FB + sgrp);
    }
#pragma unroll
    for (int i = 0; i < 2; ++i) {
        const int row = i * 64 + srow;
        *(f16x8*)&Asx[row][sgrp] = nA[i];
        *(f16x8*)&Bsx[row][sgrp] = nB[i];
    }
    __syncthreads();

#pragma unroll 1
    for (int kt = 0; kt < 16; ++kt) {
        if (kt < 15) {
            const int k0 = (kt + 1) * 32;
#pragma unroll
            for (int i = 0; i < 2; ++i) {
                const int row = i * 64 + srow;
                nA[i] = *(const f16x8*)(A + (i64)(m0 + row) * FB + k0 + sgrp);
                nB[i] = *(const f16x8*)(Bsrc + (i64)(t0 + row) * FB + k0 + sgrp);
            }
        }
        f16x8 aA[4], bB[4];
#pragma unroll
        for (int mf = 0; mf < 4; ++mf)
            aA[mf] = *(const f16x8*)&Asx[wm * 64 + mf * 16 + lr][lg * 8];
#pragma unroll
        for (int nf = 0; nf < 4; ++nf)
            bB[nf] = *(const f16x8*)&Bsx[wn * 64 + nf * 16 + lr][lg * 8];
#pragma unroll
        for (int nf = 0; nf < 4; ++nf)
#pragma unroll
            for (int mf = 0; mf < 4; ++mf)
                acc[mf][nf] = MFMA16(aA[mf], bB[nf], acc[mf][nf]);
        __syncthreads();
        if (kt < 15) {
#pragma unroll
            for (int i = 0; i < 2; ++i) {
                const int row = i * 64 + srow;
                *(f16x8*)&Asx[row][sgrp] = nA[i];
                *(f16x8*)&Bsx[row][sgrp] = nB[i];
            }
        }
        __syncthreads();
    }

#pragma unroll
    for (int mf = 0; mf < 4; ++mf) {
        const int m = m0 + wm * 64 + mf * 16 + lg * 4;
        const float4 bv = *(const float4*)&bias[m];
        const float bb[4] = {bv.x, bv.y, bv.z, bv.w};
#pragma unroll
        for (int nf = 0; nf < 4; ++nf) {
            const int t = t0 + wn * 64 + nf * 16 + lr;
            f16x4 o;
#pragma unroll
            for (int r = 0; r < 4; ++r) o[r] = (f16)(acc[mf][nf][r] + bb[r]);
            *(f16x4*)&Odst[(i64)t * FB + m] = o;
        }
    }
}

// 3D-grid launcher (used for Weff = W2@W1: A=W1t, In=W2h, bias=0)
__global__ __launch_bounds__(256, 2) void k_rgemm(const f16* __restrict__ A,
                                                  const f16* __restrict__ In,
                                                  const float* __restrict__ bias,
                                                  f16* __restrict__ Out) {
    __shared__ f16 Asx[128][40], Bsx[128][40];
    rgemm_body(A, In, bias, Out, blockIdx.x * 128, blockIdx.y * 128, blockIdx.z,
               Asx, Bsx);
}

// XCD-grouped 1D launcher for logits GEMM (r13: +L2 tile reuse)
__global__ __launch_bounds__(256, 2) void k_rgemm_swz(const f16* __restrict__ A,
                                                      const f16* __restrict__ In,
                                                      const float* __restrict__ bias,
                                                      f16* __restrict__ Out) {
    __shared__ f16 Asx[128][40], Bsx[128][40];
    const int id = blockIdx.x;
    const int xcd = id & 7, q = id >> 3;
    const int m = q & 3;
    const int G = ((q >> 2) << 3) | xcd;
    rgemm_body(A, In, bias, Out, (G & 1) * 128, m * 128, G >> 1, Asx, Bsx);
}

// ================= fused softmax + conjFFT/mul/FFT, radix-8 three-step =======
// r16 configuration (empirical optimum): x2-wide, 32 KB XOR-swizzled LDS,
// direct coalesced global I/O (lane-stride-1 element = 128B/instruction),
// no explicit prefetch hoist, no setprio (r17 x4-wide and r18 prefetch+prio
// both measured neutral-to-negative). Stores reordered stream-major.

#define TWO_PI_OVER_512 0.012271846303085129f
#define TWO_PI_OVER_64 0.0981747704246810387f
#define R2C 0.70710678118654752f

__device__ __forceinline__ int swz(int r, int c) { return r * 8 + (c ^ (r & 7)); }

template <int SGN>
__device__ __forceinline__ void fft8(float xr[8], float xi[8]) {
    const float sg = (float)SGN;   // W8 = e^{SGN*i*2pi/8}
    float t0r = xr[0] + xr[4], t0i = xi[0] + xi[4];
    float u0r = xr[0] - xr[4], u0i = xi[0] - xi[4];
    float t1r = xr[1] + xr[5], t1i = xi[1] + xi[5];
    float d1r = xr[1] - xr[5], d1i = xi[1] - xi[5];
    float u1r = R2C * (d1r - sg * d1i), u1i = R2C * (sg * d1r + d1i);
    float t2r = xr[2] + xr[6], t2i = xi[2] + xi[6];
    float d2r = xr[2] - xr[6], d2i = xi[2] - xi[6];
    float u2r = -sg * d2i, u2i = sg * d2r;
    float t3r = xr[3] + xr[7], t3i = xi[3] + xi[7];
    float d3r = xr[3] - xr[7], d3i = xi[3] - xi[7];
    float u3r = -R2C * (d3r + sg * d3i), u3i = R2C * (sg * d3r - d3i);
    float p0r = t0r + t2r, p0i = t0i + t2i, q0r = t0r - t2r, q0i = t0i - t2i;
    float p1r = t1r + t3r, p1i = t1i + t3i;
    float q1r = -sg * (t1i - t3i), q1i = sg * (t1r - t3r);
    float p2r = u0r + u2r, p2i = u0i + u2i, q2r = u0r - u2r, q2i = u0i - u2i;
    float p3r = u1r + u3r, p3i = u1i + u3i;
    float q3r = -sg * (u1i - u3i), q3i = sg * (u1r - u3r);
    xr[0] = p0r + p1r; xi[0] = p0i + p1i;
    xr[4] = p0r - p1r; xi[4] = p0i - p1i;
    xr[2] = q0r + q1r; xi[2] = q0i + q1i;
    xr[6] = q0r - q1r; xi[6] = q0i - q1i;
    xr[1] = p2r + p3r; xi[1] = p2i + p3i;
    xr[5] = p2r - p3r; xi[5] = p2i - p3i;
    xr[3] = q2r + q3r; xi[3] = q2i + q3i;
    xr[7] = q2r - q3r; xi[7] = q2i - q3i;
}

template <int SGN>
__device__ __forceinline__ void fft512x2(float ar[8], float ai[8],
                                         float br[8], float bi[8], int lane,
                                         float4* __restrict__ L,
                                         const float w1c[7], const float w1s[7],
                                         const float w2c[7], const float w2s[7]) {
    const float sg = (float)SGN;
    fft8<SGN>(ar, ai);
    fft8<SGN>(br, bi);
#pragma unroll
    for (int m = 1; m < 8; ++m) {
        const float wc = w1c[m - 1], ws = sg * w1s[m - 1];
        float tr = ar[m], ti = ai[m];
        ar[m] = tr * wc - ti * ws; ai[m] = tr * ws + ti * wc;
        tr = br[m]; ti = bi[m];
        br[m] = tr * wc - ti * ws; bi[m] = tr * ws + ti * wc;
    }
    // transpose 1: linear write (lane, m) ; permuted read (a8+8b8, m8)
#pragma unroll
    for (int m = 0; m < 8; ++m)
        L[swz(lane, m)] = make_float4(ar[m], ai[m], br[m], bi[m]);
    {
        const int a8 = lane & 7, m8 = lane >> 3;
#pragma unroll
        for (int b8 = 0; b8 < 8; ++b8) {
            const float4 v = L[swz(a8 + 8 * b8, m8)];
            ar[b8] = v.x; ai[b8] = v.y; br[b8] = v.z; bi[b8] = v.w;
        }
    }
    fft8<SGN>(ar, ai);
    fft8<SGN>(br, bi);
#pragma unroll
    for (int n = 1; n < 8; ++n) {
        const float wc = w2c[n - 1], ws = sg * w2s[n - 1];
        float tr = ar[n], ti = ai[n];
        ar[n] = tr * wc - ti * ws; ai[n] = tr * ws + ti * wc;
        tr = br[n]; ti = bi[n];
        br[n] = tr * wc - ti * ws; bi[n] = tr * ws + ti * wc;
    }
    // transpose 2: scatter write (m2+8n, a2) ; linear read (lane, j)
    {
        const int a2 = lane & 7, m2 = lane >> 3;
#pragma unroll
        for (int n = 0; n < 8; ++n)
            L[swz(m2 + 8 * n, a2)] = make_float4(ar[n], ai[n], br[n], bi[n]);
    }
#pragma unroll
    for (int j = 0; j < 8; ++j) {
        const float4 v = L[swz(lane, j)];
        ar[j] = v.x; ai[j] = v.y; br[j] = v.z; bi[j] = v.w;
    }
    fft8<SGN>(ar, ai);
    fft8<SGN>(br, bi);
}

__device__ __forceinline__ float wave_max(float v) {
#pragma unroll
    for (int m = 1; m <= 32; m <<= 1) v = fmaxf(v, __shfl_xor(v, m));
    return v;
}
__device__ __forceinline__ float wave_sum(float v) {
#pragma unroll
    for (int m = 1; m <= 32; m <<= 1) v += __shfl_xor(v, m);
    return v;
}

__device__ __forceinline__ void softmax8(float w[8]) {
    float mx = w[0];
#pragma unroll
    for (int j = 1; j < 8; ++j) mx = fmaxf(mx, w[j]);
    mx = wave_max(mx);
    float sm = 0.f;
#pragma unroll
    for (int j = 0; j < 8; ++j) { w[j] = __expf(w[j] - mx); sm += w[j]; }
    sm = wave_sum(sm);
    const float inv = 1.0f / sm;
#pragma unroll
    for (int j = 0; j < 8; ++j) w[j] *= inv;
}

__device__ __forceinline__ void fftconv_block(const f16* __restrict__ xh,
                                              const f16* __restrict__ logits,
                                              f16* __restrict__ conv,
                                              int tblk, int cs,
                                              int wave, int lane, float4* L) {
    const int b = cs >> 4, d = cs & 15;
    const int pre = b * 32 + d;
    const int pim = pre + 16;

    float w1c[7], w1s[7], w2c[7], w2s[7];
    {
        float s1, c1;
        __sincosf((float)lane * TWO_PI_OVER_512, &s1, &c1);
        w1c[0] = c1; w1s[0] = s1;
#pragma unroll
        for (int m = 1; m < 7; ++m) {
            const float pc = w1c[m - 1], ps = w1s[m - 1];
            w1c[m] = pc * c1 - ps * s1;
            w1s[m] = pc * s1 + ps * c1;
        }
        float s2, c2;
        __sincosf((float)(lane & 7) * TWO_PI_OVER_64, &s2, &c2);
        w2c[0] = c2; w2s[0] = s2;
#pragma unroll
        for (int n = 1; n < 7; ++n) {
            const float pc = w2c[n - 1], ps = w2s[n - 1];
            w2c[n] = pc * c2 - ps * s2;
            w2s[n] = pc * s2 + ps * c2;
        }
    }

    const f16* Hre = xh + (i64)pre * PLANE;
    const f16* Him = xh + (i64)pim * PLANE;
    const f16* Wre = logits + (i64)pre * PLANE;
    const f16* Wim = logits + (i64)pim * PLANE;
    f16* Cre = conv + (i64)pre * PLANE;
    f16* Cim = conv + (i64)pim * PLANE;

    const int t1a = tblk * 8 + wave * 2;
    const i64 rb0 = (i64)t1a * FB + lane;
    const i64 rb1 = rb0 + FB;

    float p0r[8], p0i[8], p1r[8], p1i[8];
    {
        float hr[8], hi2[8], wr[8], wi[8];
#pragma unroll
        for (int j = 0; j < 8; ++j) {
            hr[j] = (float)Hre[rb0 + 64 * j];
            hi2[j] = (float)Him[rb0 + 64 * j];
            wr[j] = (float)Wre[rb0 + 64 * j];
            wi[j] = (float)Wim[rb0 + 64 * j];
        }
        softmax8(wr);
        softmax8(wi);
        fft512x2<1>(hr, hi2, wr, wi, lane, L, w1c, w1s, w2c, w2s);
#pragma unroll
        for (int j = 0; j < 8; ++j) {
            p0r[j] = (hr[j] * wr[j] - hi2[j] * wi[j]) * (1.0f / 512.0f);
            p0i[j] = (hr[j] * wi[j] + hi2[j] * wr[j]) * (1.0f / 512.0f);
        }
    }
    {
        float hr[8], hi2[8], wr[8], wi[8];
#pragma unroll
        for (int j = 0; j < 8; ++j) {
            hr[j] = (float)Hre[rb1 + 64 * j];
            hi2[j] = (float)Him[rb1 + 64 * j];
            wr[j] = (float)Wre[rb1 + 64 * j];
            wi[j] = (float)Wim[rb1 + 64 * j];
        }
        softmax8(wr);
        softmax8(wi);
        fft512x2<1>(hr, hi2, wr, wi, lane, L, w1c, w1s, w2c, w2s);
#pragma unroll
        for (int j = 0; j < 8; ++j) {
            p1r[j] = (hr[j] * wr[j] - hi2[j] * wi[j]) * (1.0f / 512.0f);
            p1i[j] = (hr[j] * wi[j] + hi2[j] * wr[j]) * (1.0f / 512.0f);
        }
    }
    fft512x2<-1>(p0r, p0i, p1r, p1i, lane, L, w1c, w1s, w2c, w2s);

    // direct coalesced stores, stream-major (sequential 128B lines per stream)
#pragma unroll
    for (int s = 0; s < 8; ++s) Cre[rb0 + 64 * s] = (f16)p0r[s];
#pragma unroll
    for (int s = 0; s < 8; ++s) Cim[rb0 + 64 * s] = (f16)p0i[s];
#pragma unroll
    for (int s = 0; s < 8; ++s) Cre[rb1 + 64 * s] = (f16)p1r[s];
#pragma unroll
    for (int s = 0; s < 8; ++s) Cim[rb1 + 64 * s] = (f16)p1i[s];
}

// Single-pass fftconv over all 128 pairs, XCD-swizzled (r13).
__global__ __launch_bounds__(256, 2) void k_fftconv_all(const f16* __restrict__ xh,
                                                        const f16* __restrict__ logits,
                                                        f16* __restrict__ conv) {
    __shared__ float4 LDS[4][512];   // 32 KB
    const int id = blockIdx.x;
    const int xcd = id & 7, r = id >> 3;
    const int tblk = r & 31;
    const int cs = (xcd << 4) | (r >> 5);
    const int wave = threadIdx.x >> 6, lane = threadIdx.x & 63;
    fftconv_block(xh, logits, conv, tblk, cs, wave, lane, LDS[wave]);
}

// transpose_out: f16 [t][f] conv plane p -> f32 [f][t] out plane p
__global__ __launch_bounds__(256) void k_transpose_out(const f16* __restrict__ C,
                                                       float* __restrict__ O) {
    __shared__ float ld[64][65];
    const int tid = threadIdx.x;
    const int p = blockIdx.z;
    const f16* src = C + (i64)p * PLANE;
    float* dst = O + (i64)p * PLANE;
    const int t0 = blockIdx.x * 64, f0 = blockIdx.y * 64;
    const int tr = tid >> 3, fc = (tid & 7) * 8;
    f16x8 u0 = *(const f16x8*)&src[(i64)(t0 + tr) * FB + f0 + fc];
    f16x8 u1 = *(const f16x8*)&src[(i64)(t0 + tr + 32) * FB + f0 + fc];
#pragma unroll
    for (int j = 0; j < 8; ++j) {
        ld[fc + j][tr] = (float)u0[j];
        ld[fc + j][tr + 32] = (float)u1[j];
    }
    __syncthreads();
    const int fr = tid >> 4, tc = (tid & 15) * 4;
#pragma unroll
    for (int i = 0; i < 4; ++i) {
        const int f = fr + i * 16;
        float4 o;
        o.x = ld[f][tc + 0]; o.y = ld[f][tc + 1];
        o.z = ld[f][tc + 2]; o.w = ld[f][tc + 3];
        *(float4*)&dst[(i64)(f0 + f) * TB + t0 + tc] = o;
    }
}

extern "C" void kernel_launch(void* const* d_in, const int* in_sizes, int n_in,
                              void* d_out, int out_size, void* d_ws, size_t ws_size,
                              hipStream_t stream) {
    (void)in_sizes; (void)n_in; (void)out_size; (void)ws_size;
    const float* x = (const float*)d_in[0];
    const float* W1 = (const float*)d_in[1];
    const float* b1 = (const float*)d_in[2];
    const float* W2 = (const float*)d_in[3];
    const float* b2 = (const float*)d_in[4];
    float* out = (float*)d_out;

    char* ws = (char*)d_ws;
    const i64 TENB = (i64)67108864;                       // f16 full tensor bytes
    f16* Weff  = (f16*)(ws);                              // 512 KB
    float* beff = (float*)(ws + 524288);                  // 2 KB (pad to 4 KB)
    f16* W1t  = (f16*)(ws + 528384);                      // 512 KB
    f16* W2h  = (f16*)(ws + 1052672);                     // 512 KB
    float* zrs = (float*)(ws + 1576960);                  // 2 KB (pad to 4 KB)
    f16* xh     = (f16*)(ws + 1581056);                   // 67.1 MB
    f16* logits = (f16*)(ws + 1581056 + TENB);            // 67.1 MB
    f16* conv   = (f16*)(ws + 1581056 + 2 * TENB);        // 67.1 MB

    // L1: x-tcvt || W1^T-tcvt || W2-cvt || zeros || beff (wave-parallel)
    k_pre2<<<dim3(8513), dim3(256), 0, stream>>>(x, xh, W1, W1t, W2, W2h, zrs, b1, b2, beff);
    // L2: Weff = W2 @ W1 via MFMA
    k_rgemm<<<dim3(4, 4, 1), dim3(256), 0, stream>>>(W1t, W2h, zrs, Weff);
    // L3: logits = Weff @ X + beff (XCD-grouped: In-tile shared via L2)
    k_rgemm_swz<<<dim3(2048), dim3(256), 0, stream>>>(Weff, xh, beff, logits);
    // L4: fftconv all 128 pairs -> conv f16
    k_fftconv_all<<<dim3(4096), dim3(256), 0, stream>>>(xh, logits, conv);
    // L5: transpose conv -> out (f32 [f][t], all 256 planes)
    k_transpose_out<<<dim3(4, 8, 256), dim3(256), 0, stream>>>(conv, out);
}